// Round 1
// baseline (287.082 us; speedup 1.0000x reference)
//
#include <hip/hip_runtime.h>

// EdgewiseReduce: out[n, :] = sum over edges e with center[e]==n of feat[e, :]
// center is sorted -> build CSR offsets, then one wave per node, no atomics.

#define D_FEAT 64

// Kernel 1: build row offsets from sorted center array.
// offsets[n] = first edge index with center >= n; offsets[N] = E.
__global__ void build_offsets_kernel(const int* __restrict__ center,
                                     int* __restrict__ offsets,
                                     int E, int N) {
    int e = blockIdx.x * blockDim.x + threadIdx.x;
    if (e >= E) return;
    int c = center[e];
    int prev = (e == 0) ? -1 : center[e - 1];
    // fill gap (handles nodes with zero edges and the leading range)
    for (int n = prev + 1; n <= c; ++n) offsets[n] = e;
    if (e == E - 1) {
        for (int n = c + 1; n <= N; ++n) offsets[n] = E;
    }
}

// Kernel 2: one wave per node. 64 lanes = 4 edge-groups x 16 dim-quads.
// Each lane float4-loads (16B) its dim-quad for every 4th edge; cross-group
// shfl_xor reduce; lanes 0..15 store the node row as float4.
__global__ __launch_bounds__(256) void segment_sum_kernel(
        const float* __restrict__ feat,
        const int* __restrict__ offsets,
        float* __restrict__ out, int N) {
    const int wave = threadIdx.x >> 6;
    const int lane = threadIdx.x & 63;
    const int node = blockIdx.x * 4 + wave;
    if (node >= N) return;

    const int start = offsets[node];
    const int end   = offsets[node + 1];
    const int sub = lane & 15;   // which float4 of the 64-dim row
    const int grp = lane >> 4;   // which edge subset (0..3)

    float4 acc = make_float4(0.f, 0.f, 0.f, 0.f);
    for (int e = start + grp; e < end; e += 4) {
        const float4 v = *(const float4*)(feat + (size_t)e * D_FEAT + sub * 4);
        acc.x += v.x; acc.y += v.y; acc.z += v.z; acc.w += v.w;
    }

    // reduce across the 4 groups (lane bits 4 and 5)
    #pragma unroll
    for (int m = 32; m >= 16; m >>= 1) {
        acc.x += __shfl_xor(acc.x, m, 64);
        acc.y += __shfl_xor(acc.y, m, 64);
        acc.z += __shfl_xor(acc.z, m, 64);
        acc.w += __shfl_xor(acc.w, m, 64);
    }

    if (grp == 0) {
        *(float4*)(out + (size_t)node * D_FEAT + sub * 4) = acc;
    }
}

extern "C" void kernel_launch(void* const* d_in, const int* in_sizes, int n_in,
                              void* d_out, int out_size, void* d_ws, size_t ws_size,
                              hipStream_t stream) {
    const int*   edge_index = (const int*)d_in[0];   // [2, E], row 0 = center
    const float* edge_feat  = (const float*)d_in[1]; // [E, 64]
    // d_in[2] = node_types [N,1], only used for N

    const int E = in_sizes[0] / 2;
    const int N = in_sizes[2];

    const int* center = edge_index;          // row 0
    int* offsets = (int*)d_ws;               // N+1 ints of scratch

    build_offsets_kernel<<<(E + 255) / 256, 256, 0, stream>>>(center, offsets, E, N);
    segment_sum_kernel<<<(N + 3) / 4, 256, 0, stream>>>(edge_feat, offsets,
                                                        (float*)d_out, N);
}